// Round 1
// baseline (16082.048 us; speedup 1.0000x reference)
//
#include <hip/hip_runtime.h>
#include <cstdint>
#include <cstdio>

// CustomLSTM: B=64, T=512, D=H=1024.  f16 MFMA pipeline:
//   k_init    : h0 -> f16 ping buffer, zero barrier counters
//   k_castx   : input_seq fp32 -> f16
//   k_weights : build permuted f16 Wi[4096][1024], Wh[4096][1024]
//               row perm p = nb*64 + gate*16 + uu  (nb=unit-block, uu=unit%16)
//   k_gemm    : x_proj[32768][4096] f16 = X @ Wi^T   (128x128 tile, mfma 16x16x32)
//   k_rnn     : persistent scan, 256 WGs (1/CU), Wh slice in LDS, custom
//               per-batch-block device barrier each step.

typedef _Float16 half8 __attribute__((ext_vector_type(8)));
typedef _Float16 half4 __attribute__((ext_vector_type(4)));
typedef float f32x4 __attribute__((ext_vector_type(4)));

typedef __attribute__((address_space(1))) uint32_t gu32;
typedef __attribute__((address_space(3))) uint32_t lu32;

#define MFMA16(a, b, c) __builtin_amdgcn_mfma_f32_16x16x32_f16((a), (b), (c), 0, 0, 0)

// workspace layout (bytes)
#define XP_OFF   0ull                 // x_proj f16 [32768][4096]  = 256 MB
#define AH_OFF   268435456ull         // input f16  [32768][1024]  =  64 MB
#define WI_OFF   335544320ull         // Wi_perm f16 [4096][1024]  =   8 MB
#define WH_OFF   343932928ull         // Wh_perm f16 [4096][1024]  =   8 MB
#define HBF_OFF  352321536ull         // h f16 ping-pong [2][64][1024] = 256 KB
#define CNT_OFF  352583680ull         // 4 barrier counters, stride 64 ints
#define WS_NEED  352584704ull

__device__ inline float sigmoid_f(float x) { return 1.f / (1.f + __expf(-x)); }
__device__ inline float tanh_f(float x) {
  float ax = fabsf(x);
  float e = __expf(-2.f * ax);          // in (0,1], no overflow
  float t = (1.f - e) / (1.f + e);
  return x < 0.f ? -t : t;
}

__global__ void k_init(const float* __restrict__ h0, _Float16* __restrict__ hbf,
                       int* __restrict__ cnt) {
  int i = blockIdx.x * 256 + threadIdx.x;
  hbf[i] = (_Float16)h0[i];
  if (blockIdx.x == 0) cnt[threadIdx.x] = 0;
}

__global__ void k_castx(const float* __restrict__ x, _Float16* __restrict__ xh) {
  size_t i = ((size_t)blockIdx.x * 256 + threadIdx.x) * 8;
  float4 a = *(const float4*)(x + i);
  float4 b = *(const float4*)(x + i + 4);
  half8 o = {(_Float16)a.x, (_Float16)a.y, (_Float16)a.z, (_Float16)a.w,
             (_Float16)b.x, (_Float16)b.y, (_Float16)b.z, (_Float16)b.w};
  *(half8*)(xh + i) = o;
}

// 8192 blocks: 0..4095 -> Wi rows, 4096..8191 -> Wh rows. 256 thr x 4 cols.
__global__ void k_weights(const float* __restrict__ Wii, const float* __restrict__ Wif,
                          const float* __restrict__ Wig, const float* __restrict__ Wio,
                          const float* __restrict__ Whi, const float* __restrict__ Whf,
                          const float* __restrict__ Whg, const float* __restrict__ Who,
                          _Float16* __restrict__ WI, _Float16* __restrict__ WH) {
  int r = blockIdx.x;
  int p = r & 4095;
  int nb = p >> 6, gi = (p >> 4) & 3, uu = p & 15;
  int srow = nb * 16 + uu;
  const float* src;
  if (r < 4096) src = (gi == 0 ? Wii : gi == 1 ? Wif : gi == 2 ? Wig : Wio);
  else          src = (gi == 0 ? Whi : gi == 1 ? Whf : gi == 2 ? Whg : Who);
  src += (size_t)srow * 1024;
  _Float16* dst = (r < 4096 ? WI : WH) + (size_t)p * 1024;
  int c = threadIdx.x * 4;
  float4 v = *(const float4*)(src + c);
  half4 o = {(_Float16)v.x, (_Float16)v.y, (_Float16)v.z, (_Float16)v.w};
  *(half4*)(dst + c) = o;
}

// x_proj = A[32768][1024] @ B[4096][1024]^T, f16 out. 128x128 tile, BK=32.
__global__ __launch_bounds__(256) void k_gemm(const _Float16* __restrict__ A,
                                              const _Float16* __restrict__ B,
                                              _Float16* __restrict__ XPo) {
  __shared__ __align__(16) _Float16 As[128 * 32];
  __shared__ __align__(16) _Float16 Bs[128 * 32];
  const int tid = threadIdx.x;
  const int w = tid >> 6, l = tid & 63;
  const int wm = w >> 1, wn = w & 1;
  const int lm = l & 15, lq = l >> 4;
  const size_t m0 = (size_t)blockIdx.x * 128;
  const size_t n0 = (size_t)blockIdx.y * 128;

  f32x4 acc[4][4] = {};

  // staging: slot s (0..511) -> LDS bytes s*16; row = s>>2, kchunk = s&3
  const int r0 = tid >> 2, c0_ = tid & 3;
  const int r1 = (256 + tid) >> 2, c1_ = tid & 3;
  const _Float16* ga0 = A + (m0 + r0) * 1024 + c0_ * 8;
  const _Float16* ga1 = A + (m0 + r1) * 1024 + c1_ * 8;
  const _Float16* gb0 = B + (n0 + r0) * 1024 + c0_ * 8;
  const _Float16* gb1 = B + (n0 + r1) * 1024 + c1_ * 8;
  _Float16* laBase = As + (size_t)w * 512;   // wave-uniform LDS base (+lane*16 by HW)
  _Float16* lbBase = Bs + (size_t)w * 512;

  for (int kt = 0; kt < 32; ++kt) {
    const int k0 = kt * 32;
    __syncthreads();
    __builtin_amdgcn_global_load_lds((gu32*)(ga0 + k0), (lu32*)laBase, 16, 0, 0);
    __builtin_amdgcn_global_load_lds((gu32*)(ga1 + k0), (lu32*)(laBase + 2048), 16, 0, 0);
    __builtin_amdgcn_global_load_lds((gu32*)(gb0 + k0), (lu32*)lbBase, 16, 0, 0);
    __builtin_amdgcn_global_load_lds((gu32*)(gb1 + k0), (lu32*)(lbBase + 2048), 16, 0, 0);
    __syncthreads();

    half8 af[4], bf[4];
#pragma unroll
    for (int mi = 0; mi < 4; ++mi)
      af[mi] = *(const half8*)(As + (size_t)(wm * 64 + mi * 16 + lm) * 32 + lq * 8);
#pragma unroll
    for (int ni = 0; ni < 4; ++ni)
      bf[ni] = *(const half8*)(Bs + (size_t)(wn * 64 + ni * 16 + lm) * 32 + lq * 8);
#pragma unroll
    for (int mi = 0; mi < 4; ++mi)
#pragma unroll
      for (int ni = 0; ni < 4; ++ni)
        acc[mi][ni] = MFMA16(af[mi], bf[ni], acc[mi][ni]);
  }

#pragma unroll
  for (int mi = 0; mi < 4; ++mi) {
#pragma unroll
    for (int r = 0; r < 4; ++r) {
      size_t m = m0 + wm * 64 + mi * 16 + lq * 4 + r;  // D row=(l>>4)*4+r, col=l&15
      _Float16* orow = XPo + m * 4096 + n0 + wn * 64 + lm;
#pragma unroll
      for (int ni = 0; ni < 4; ++ni) orow[ni * 16] = (_Float16)acc[mi][ni][r];
    }
  }
}

// Persistent scan. WG = (mb = bid&3: 16 batches, nb = bid>>2: 16 units).
__global__ __launch_bounds__(256, 1) void k_rnn(
    const _Float16* __restrict__ XP, const _Float16* __restrict__ WH,
    const float* __restrict__ c0,
    const float* __restrict__ bI, const float* __restrict__ bF,
    const float* __restrict__ bG, const float* __restrict__ bO,
    _Float16* __restrict__ hbf, int* __restrict__ cnt, float* __restrict__ out) {
  __shared__ __align__(16) char smem[147456];
  _Float16* wl = (_Float16*)smem;         // Wh slice swizzled [kc=128][row=64][8]
  float* red = (float*)(smem + 131072);   // [wave=4][batch=16][p=64]

  const int tid = threadIdx.x;
  const int mb = blockIdx.x & 3;
  const int nb = blockIdx.x >> 2;

  // fill Wh LDS: slot s -> bytes s*16, row = s&63, kc = s>>6 (conflict-free writes)
  const _Float16* wsrc = WH + (size_t)nb * 64 * 1024;
#pragma unroll 4
  for (int it = 0; it < 32; ++it) {
    int s = it * 256 + tid;
    int row = s & 63, kc = s >> 6;
    *(half8*)(wl + (size_t)s * 8) = *(const half8*)(wsrc + (size_t)row * 1024 + kc * 8);
  }

  const int w = tid >> 6, l = tid & 63;
  const int lm = l & 15, lq = l >> 4;
  const int bl = tid >> 4, uu = tid & 15;
  const int bgrow = mb * 16 + bl;   // global batch (finalize role)
  const int u = nb * 16 + uu;       // global unit  (finalize role)

  float c = c0[(size_t)bgrow * 1024 + u];
  const float bias0 = bI[u], bias1 = bF[u], bias2 = bG[u], bias3 = bO[u];
  const size_t xpth = (size_t)bgrow * 512 * 4096 + (size_t)nb * 64 + uu;
  int* mycnt = cnt + mb * 64;       // 256-B padded counters

  __syncthreads();

  for (int t = 0; t < 512; ++t) {
    // prefetch this step's x_proj contributions (independent of h)
    const size_t xb = xpth + (size_t)t * 4096;
    float xv0 = (float)XP[xb];
    float xv1 = (float)XP[xb + 16];
    float xv2 = (float)XP[xb + 32];
    float xv3 = (float)XP[xb + 48];

    // gates partial: wave w covers k in [w*256, w*256+256)
    const _Float16* hr = hbf + (size_t)(t & 1) * 65536 + (size_t)(mb * 16 + lm) * 1024 + lq * 8;
    f32x4 a0 = {0.f, 0.f, 0.f, 0.f}, a1 = a0, a2 = a0, a3 = a0;
#pragma unroll
    for (int kk = 0; kk < 8; ++kk) {
      const int k0 = w * 256 + kk * 32;
      half8 av = *(const half8*)(hr + k0);
      const _Float16* bb = wl + (size_t)(k0 / 8 + lq) * 512 + lm * 8;
      a0 = MFMA16(av, *(const half8*)(bb), a0);
      a1 = MFMA16(av, *(const half8*)(bb + 128), a1);
      a2 = MFMA16(av, *(const half8*)(bb + 256), a2);
      a3 = MFMA16(av, *(const half8*)(bb + 384), a3);
    }
#pragma unroll
    for (int r = 0; r < 4; ++r) {   // D: row=(l>>4)*4+r (batch), col=l&15
      float* rr = red + (size_t)(w * 16 + lq * 4 + r) * 64 + lm;
      rr[0] = a0[r]; rr[16] = a1[r]; rr[32] = a2[r]; rr[48] = a3[r];
    }
    __syncthreads();

    // finalize: thread = (batch bl, unit uu)
    float p0 = xv0 + bias0, p1 = xv1 + bias1, p2 = xv2 + bias2, p3 = xv3 + bias3;
#pragma unroll
    for (int ww = 0; ww < 4; ++ww) {
      const float* rr = red + (size_t)(ww * 16 + bl) * 64 + uu;
      p0 += rr[0]; p1 += rr[16]; p2 += rr[32]; p3 += rr[48];
    }
    float ig = sigmoid_f(p0), fg = sigmoid_f(p1), gg = tanh_f(p2), og = sigmoid_f(p3);
    c = fg * c + ig * gg;
    float h = og * tanh_f(c);

    out[(size_t)(bgrow * 512 + t) * 1024 + u] = h;
    hbf[(size_t)((t + 1) & 1) * 65536 + (size_t)bgrow * 1024 + u] = (_Float16)h;
    if (t == 511) {
      out[33554432u + (size_t)bgrow * 1024 + u] = h;
      out[33554432u + 65536u + (size_t)bgrow * 1024 + u] = c;
    }

    // device barrier among the 64 WGs sharing this batch-block
    __threadfence();
    __syncthreads();
    if (tid == 0) {
      __hip_atomic_fetch_add(mycnt, 1, __ATOMIC_RELEASE, __HIP_MEMORY_SCOPE_AGENT);
      const int target = 64 * (t + 1);
      while (__hip_atomic_load(mycnt, __ATOMIC_ACQUIRE, __HIP_MEMORY_SCOPE_AGENT) < target) {
      }
    }
    __syncthreads();
  }
}

extern "C" void kernel_launch(void* const* d_in, const int* in_sizes, int n_in,
                              void* d_out, int out_size, void* d_ws, size_t ws_size,
                              hipStream_t stream) {
  const float* x   = (const float*)d_in[0];
  const float* h0  = (const float*)d_in[1];
  const float* c0  = (const float*)d_in[2];
  const float* Wii = (const float*)d_in[3];
  const float* Whi = (const float*)d_in[4];
  const float* bI  = (const float*)d_in[5];
  const float* Wif = (const float*)d_in[6];
  const float* Whf = (const float*)d_in[7];
  const float* bF  = (const float*)d_in[8];
  const float* Wig = (const float*)d_in[9];
  const float* Whg = (const float*)d_in[10];
  const float* bG  = (const float*)d_in[11];
  const float* Wio = (const float*)d_in[12];
  const float* Who = (const float*)d_in[13];
  const float* bO  = (const float*)d_in[14];
  float* out = (float*)d_out;

  if (ws_size < WS_NEED) {
    fprintf(stderr, "kernel_launch: ws too small (%zu < %llu)\n", ws_size,
            (unsigned long long)WS_NEED);
    return;
  }
  char* ws = (char*)d_ws;
  _Float16* XP  = (_Float16*)(ws + XP_OFF);
  _Float16* AH  = (_Float16*)(ws + AH_OFF);
  _Float16* WI  = (_Float16*)(ws + WI_OFF);
  _Float16* WH  = (_Float16*)(ws + WH_OFF);
  _Float16* HBF = (_Float16*)(ws + HBF_OFF);
  int* CNT = (int*)(ws + CNT_OFF);

  k_init<<<256, 256, 0, stream>>>(h0, HBF, CNT);
  k_castx<<<16384, 256, 0, stream>>>(x, AH);
  k_weights<<<8192, 256, 0, stream>>>(Wii, Wif, Wig, Wio, Whi, Whf, Whg, Who, WI, WH);
  k_gemm<<<dim3(256, 32), 256, 0, stream>>>(AH, WI, XP);
  k_rnn<<<256, 256, 0, stream>>>(XP, WH, c0, bI, bF, bG, bO, HBF, CNT, out);
}

// Round 2
// 3144.237 us; speedup vs baseline: 5.1148x; 5.1148x over previous
//
#include <hip/hip_runtime.h>
#include <cstdint>
#include <cstdio>

// CustomLSTM: B=64, T=512, D=H=1024.  f16 MFMA pipeline:
//   k_init    : h0 -> f16 ping buffer, zero barrier counters
//   k_castx   : input_seq fp32 -> f16
//   k_weights : build permuted f16 Wi[4096][1024], Wh[4096][1024]
//               row perm p = nb*64 + gate*16 + uu  (nb=unit-block, uu=unit%16)
//   k_gemm    : x_proj[32768][4096] f16 = X @ Wi^T   (128x128 tile, mfma 16x16x32)
//   k_rnn     : persistent scan, 256 WGs (1/CU), Wh slice in LDS.
//               Sync redesign (R1): NO threadfence / acquire-release in the
//               step loop — h exchange via relaxed agent-scope (sc1) atomics
//               that bypass L2 to the L3 coherence point; ordering via raw
//               s_waitcnt vmcnt(0) + relaxed counter barrier per batch-block.

typedef _Float16 half8 __attribute__((ext_vector_type(8)));
typedef _Float16 half4 __attribute__((ext_vector_type(4)));
typedef float f32x4 __attribute__((ext_vector_type(4)));

typedef __attribute__((address_space(1))) uint32_t gu32;
typedef __attribute__((address_space(3))) uint32_t lu32;

#define MFMA16(a, b, c) __builtin_amdgcn_mfma_f32_16x16x32_f16((a), (b), (c), 0, 0, 0)

// workspace layout (bytes)
#define XP_OFF   0ull                 // x_proj f16 [32768][4096]  = 256 MB
#define AH_OFF   268435456ull         // input f16  [32768][1024]  =  64 MB
#define WI_OFF   335544320ull         // Wi_perm f16 [4096][1024]  =   8 MB
#define WH_OFF   343932928ull         // Wh_perm f16 [4096][1024]  =   8 MB
#define HBF_OFF  352321536ull         // h f16 ping-pong [2][64][1024] = 256 KB
#define CNT_OFF  352583680ull         // 4 barrier counters, stride 64 ints
#define WS_NEED  352584704ull

#define RED_STRIDE 66                 // padded reduction row (floats)

__device__ inline float sigmoid_f(float x) { return 1.f / (1.f + __expf(-x)); }
__device__ inline float tanh_f(float x) {
  float ax = fabsf(x);
  float e = __expf(-2.f * ax);          // in (0,1], no overflow
  float t = (1.f - e) / (1.f + e);
  return x < 0.f ? -t : t;
}

__global__ void k_init(const float* __restrict__ h0, _Float16* __restrict__ hbf,
                       int* __restrict__ cnt) {
  int i = blockIdx.x * 256 + threadIdx.x;
  hbf[i] = (_Float16)h0[i];
  if (blockIdx.x == 0) cnt[threadIdx.x] = 0;
}

__global__ void k_castx(const float* __restrict__ x, _Float16* __restrict__ xh) {
  size_t i = ((size_t)blockIdx.x * 256 + threadIdx.x) * 8;
  float4 a = *(const float4*)(x + i);
  float4 b = *(const float4*)(x + i + 4);
  half8 o = {(_Float16)a.x, (_Float16)a.y, (_Float16)a.z, (_Float16)a.w,
             (_Float16)b.x, (_Float16)b.y, (_Float16)b.z, (_Float16)b.w};
  *(half8*)(xh + i) = o;
}

// 8192 blocks: 0..4095 -> Wi rows, 4096..8191 -> Wh rows. 256 thr x 4 cols.
__global__ void k_weights(const float* __restrict__ Wii, const float* __restrict__ Wif,
                          const float* __restrict__ Wig, const float* __restrict__ Wio,
                          const float* __restrict__ Whi, const float* __restrict__ Whf,
                          const float* __restrict__ Whg, const float* __restrict__ Who,
                          _Float16* __restrict__ WI, _Float16* __restrict__ WH) {
  int r = blockIdx.x;
  int p = r & 4095;
  int nb = p >> 6, gi = (p >> 4) & 3, uu = p & 15;
  int srow = nb * 16 + uu;
  const float* src;
  if (r < 4096) src = (gi == 0 ? Wii : gi == 1 ? Wif : gi == 2 ? Wig : Wio);
  else          src = (gi == 0 ? Whi : gi == 1 ? Whf : gi == 2 ? Whg : Who);
  src += (size_t)srow * 1024;
  _Float16* dst = (r < 4096 ? WI : WH) + (size_t)p * 1024;
  int c = threadIdx.x * 4;
  float4 v = *(const float4*)(src + c);
  half4 o = {(_Float16)v.x, (_Float16)v.y, (_Float16)v.z, (_Float16)v.w};
  *(half4*)(dst + c) = o;
}

// x_proj = A[32768][1024] @ B[4096][1024]^T, f16 out. 128x128 tile, BK=32.
__global__ __launch_bounds__(256) void k_gemm(const _Float16* __restrict__ A,
                                              const _Float16* __restrict__ B,
                                              _Float16* __restrict__ XPo) {
  __shared__ __align__(16) _Float16 As[128 * 32];
  __shared__ __align__(16) _Float16 Bs[128 * 32];
  const int tid = threadIdx.x;
  const int w = tid >> 6, l = tid & 63;
  const int wm = w >> 1, wn = w & 1;
  const int lm = l & 15, lq = l >> 4;
  const size_t m0 = (size_t)blockIdx.x * 128;
  const size_t n0 = (size_t)blockIdx.y * 128;

  f32x4 acc[4][4] = {};

  // staging: slot s (0..511) -> LDS bytes s*16; row = s>>2, kchunk = s&3
  const int r0 = tid >> 2, c0_ = tid & 3;
  const int r1 = (256 + tid) >> 2, c1_ = tid & 3;
  const _Float16* ga0 = A + (m0 + r0) * 1024 + c0_ * 8;
  const _Float16* ga1 = A + (m0 + r1) * 1024 + c1_ * 8;
  const _Float16* gb0 = B + (n0 + r0) * 1024 + c0_ * 8;
  const _Float16* gb1 = B + (n0 + r1) * 1024 + c1_ * 8;
  _Float16* laBase = As + (size_t)w * 512;   // wave-uniform LDS base (+lane*16 by HW)
  _Float16* lbBase = Bs + (size_t)w * 512;

  for (int kt = 0; kt < 32; ++kt) {
    const int k0 = kt * 32;
    __syncthreads();
    __builtin_amdgcn_global_load_lds((gu32*)(ga0 + k0), (lu32*)laBase, 16, 0, 0);
    __builtin_amdgcn_global_load_lds((gu32*)(ga1 + k0), (lu32*)(laBase + 2048), 16, 0, 0);
    __builtin_amdgcn_global_load_lds((gu32*)(gb0 + k0), (lu32*)lbBase, 16, 0, 0);
    __builtin_amdgcn_global_load_lds((gu32*)(gb1 + k0), (lu32*)(lbBase + 2048), 16, 0, 0);
    __syncthreads();

    half8 af[4], bf[4];
#pragma unroll
    for (int mi = 0; mi < 4; ++mi)
      af[mi] = *(const half8*)(As + (size_t)(wm * 64 + mi * 16 + lm) * 32 + lq * 8);
#pragma unroll
    for (int ni = 0; ni < 4; ++ni)
      bf[ni] = *(const half8*)(Bs + (size_t)(wn * 64 + ni * 16 + lm) * 32 + lq * 8);
#pragma unroll
    for (int mi = 0; mi < 4; ++mi)
#pragma unroll
      for (int ni = 0; ni < 4; ++ni)
        acc[mi][ni] = MFMA16(af[mi], bf[ni], acc[mi][ni]);
  }

#pragma unroll
  for (int mi = 0; mi < 4; ++mi) {
#pragma unroll
    for (int r = 0; r < 4; ++r) {
      size_t m = m0 + wm * 64 + mi * 16 + lq * 4 + r;  // D row=(l>>4)*4+r, col=l&15
      _Float16* orow = XPo + m * 4096 + n0 + wn * 64 + lm;
#pragma unroll
      for (int ni = 0; ni < 4; ++ni) orow[ni * 16] = (_Float16)acc[mi][ni][r];
    }
  }
}

// Persistent scan. WG = (mb = bid&3: 16 batches, nb = bid>>2: 16 units).
__global__ __launch_bounds__(256, 1) void k_rnn(
    const _Float16* __restrict__ XP, const _Float16* __restrict__ WH,
    const float* __restrict__ c0,
    const float* __restrict__ bI, const float* __restrict__ bF,
    const float* __restrict__ bG, const float* __restrict__ bO,
    _Float16* __restrict__ hbf, int* __restrict__ cnt, float* __restrict__ out) {
  __shared__ __align__(16) char smem[131072 + RED_STRIDE * 64 * 4];
  _Float16* wl = (_Float16*)smem;         // Wh slice swizzled [kc=128][row=64][8]
  float* red = (float*)(smem + 131072);   // [wave*16+batch][RED_STRIDE]

  const int tid = threadIdx.x;
  const int mb = blockIdx.x & 3;
  const int nb = blockIdx.x >> 2;

  // fill Wh LDS: slot s -> bytes s*16, row = s&63, kc = s>>6 (conflict-free writes)
  const _Float16* wsrc = WH + (size_t)nb * 64 * 1024;
#pragma unroll 4
  for (int it = 0; it < 32; ++it) {
    int s = it * 256 + tid;
    int row = s & 63, kc = s >> 6;
    *(half8*)(wl + (size_t)s * 8) = *(const half8*)(wsrc + (size_t)row * 1024 + kc * 8);
  }

  const int w = tid >> 6, l = tid & 63;
  const int lm = l & 15, lq = l >> 4;
  const int bl = tid >> 4, uu = tid & 15;
  const int bgrow = mb * 16 + bl;   // global batch (finalize role)
  const int u = nb * 16 + uu;       // global unit  (finalize role)

  float c = c0[(size_t)bgrow * 1024 + u];
  const float bias0 = bI[u], bias1 = bF[u], bias2 = bG[u], bias3 = bO[u];
  const size_t xpth = (size_t)bgrow * 512 * 4096 + (size_t)nb * 64 + uu;
  int* mycnt = cnt + mb * 64;       // 256-B padded counters

  // A-operand base (halves) within one parity buffer, for this lane's wave slice
  const size_t habase = (size_t)(mb * 16 + lm) * 1024 + (size_t)lq * 8 + (size_t)w * 256;

  // prefetch step-0 x_proj contributions
  float xn0 = (float)XP[xpth];
  float xn1 = (float)XP[xpth + 16];
  float xn2 = (float)XP[xpth + 32];
  float xn3 = (float)XP[xpth + 48];

  __syncthreads();

  for (int t = 0; t < 512; ++t) {
    const float xv0 = xn0, xv1 = xn1, xv2 = xn2, xv3 = xn3;

    // ---- h loads: relaxed agent-scope (sc1, L2-bypass), 16 in flight ----
    const uint64_t* hq =
        (const uint64_t*)(hbf + (size_t)(t & 1) * 65536 + habase);
    uint64_t hraw[16];
#pragma unroll
    for (int kk = 0; kk < 8; ++kk) {
      hraw[2 * kk] = __hip_atomic_load(hq + (size_t)kk * 8, __ATOMIC_RELAXED,
                                       __HIP_MEMORY_SCOPE_AGENT);
      hraw[2 * kk + 1] = __hip_atomic_load(hq + (size_t)kk * 8 + 1, __ATOMIC_RELAXED,
                                           __HIP_MEMORY_SCOPE_AGENT);
    }

    // ---- gates partial: wave w covers k in [w*256, w*256+256) ----
    f32x4 a0 = {0.f, 0.f, 0.f, 0.f}, a1 = a0, a2 = a0, a3 = a0;
#pragma unroll
    for (int kk = 0; kk < 8; ++kk) {
      union { uint64_t q[2]; half8 v; } av_;
      av_.q[0] = hraw[2 * kk];
      av_.q[1] = hraw[2 * kk + 1];
      const int k0 = w * 256 + kk * 32;
      const _Float16* bb = wl + (size_t)(k0 / 8 + lq) * 512 + lm * 8;
      a0 = MFMA16(av_.v, *(const half8*)(bb), a0);
      a1 = MFMA16(av_.v, *(const half8*)(bb + 128), a1);
      a2 = MFMA16(av_.v, *(const half8*)(bb + 256), a2);
      a3 = MFMA16(av_.v, *(const half8*)(bb + 384), a3);
    }
#pragma unroll
    for (int r = 0; r < 4; ++r) {   // D: row=(l>>4)*4+r (batch), col=l&15
      float* rr = red + (size_t)(w * 16 + lq * 4 + r) * RED_STRIDE + lm;
      rr[0] = a0[r]; rr[16] = a1[r]; rr[32] = a2[r]; rr[48] = a3[r];
    }
    __syncthreads();

    // ---- finalize: thread = (batch bl, unit uu) ----
    float p0 = xv0 + bias0, p1 = xv1 + bias1, p2 = xv2 + bias2, p3 = xv3 + bias3;
#pragma unroll
    for (int ww = 0; ww < 4; ++ww) {
      const float* rr = red + (size_t)(ww * 16 + bl) * RED_STRIDE + uu;
      p0 += rr[0]; p1 += rr[16]; p2 += rr[32]; p3 += rr[48];
    }
    float ig = sigmoid_f(p0), fg = sigmoid_f(p1), gg = tanh_f(p2), og = sigmoid_f(p3);
    c = fg * c + ig * gg;
    float h = og * tanh_f(c);

    out[(size_t)(bgrow * 512 + t) * 1024 + u] = h;

    // packed coherent h store (pairs of f16 via shfl; 4-byte relaxed agent store)
    uint32_t hbits = (uint32_t)__builtin_bit_cast(unsigned short, (_Float16)h);
    uint32_t other = (uint32_t)__shfl_xor((int)hbits, 1, 64);
    if ((uu & 1) == 0) {
      uint32_t packed = hbits | (other << 16);
      uint32_t* hx = (uint32_t*)(hbf + (size_t)((t + 1) & 1) * 65536);
      __hip_atomic_store(hx + ((size_t)bgrow * 1024 + u) / 2, packed,
                         __ATOMIC_RELAXED, __HIP_MEMORY_SCOPE_AGENT);
    }
    if (t == 511) {
      out[33554432u + (size_t)bgrow * 1024 + u] = h;
      out[33554432u + 65536u + (size_t)bgrow * 1024 + u] = c;
    }

    // prefetch next step's x_proj while we wait at the barrier
    if (t < 511) {
      const size_t xb = xpth + (size_t)(t + 1) * 4096;
      xn0 = (float)XP[xb];
      xn1 = (float)XP[xb + 16];
      xn2 = (float)XP[xb + 32];
      xn3 = (float)XP[xb + 48];
    }

    // ---- barrier among the 64 WGs sharing this batch-block ----
    // drain own sc1 stores (no cache maintenance!), then relaxed counter.
    asm volatile("s_waitcnt vmcnt(0)" ::: "memory");
    __syncthreads();
    if (tid == 0) {
      __hip_atomic_fetch_add(mycnt, 1, __ATOMIC_RELAXED, __HIP_MEMORY_SCOPE_AGENT);
      const int target = 64 * (t + 1);
      while (__hip_atomic_load(mycnt, __ATOMIC_RELAXED, __HIP_MEMORY_SCOPE_AGENT) <
             target) {
        __builtin_amdgcn_s_sleep(1);
      }
    }
    __syncthreads();
  }
}

extern "C" void kernel_launch(void* const* d_in, const int* in_sizes, int n_in,
                              void* d_out, int out_size, void* d_ws, size_t ws_size,
                              hipStream_t stream) {
  const float* x   = (const float*)d_in[0];
  const float* h0  = (const float*)d_in[1];
  const float* c0  = (const float*)d_in[2];
  const float* Wii = (const float*)d_in[3];
  const float* Whi = (const float*)d_in[4];
  const float* bI  = (const float*)d_in[5];
  const float* Wif = (const float*)d_in[6];
  const float* Whf = (const float*)d_in[7];
  const float* bF  = (const float*)d_in[8];
  const float* Wig = (const float*)d_in[9];
  const float* Whg = (const float*)d_in[10];
  const float* bG  = (const float*)d_in[11];
  const float* Wio = (const float*)d_in[12];
  const float* Who = (const float*)d_in[13];
  const float* bO  = (const float*)d_in[14];
  float* out = (float*)d_out;

  if (ws_size < WS_NEED) {
    fprintf(stderr, "kernel_launch: ws too small (%zu < %llu)\n", ws_size,
            (unsigned long long)WS_NEED);
    return;
  }
  char* ws = (char*)d_ws;
  _Float16* XP  = (_Float16*)(ws + XP_OFF);
  _Float16* AH  = (_Float16*)(ws + AH_OFF);
  _Float16* WI  = (_Float16*)(ws + WI_OFF);
  _Float16* WH  = (_Float16*)(ws + WH_OFF);
  _Float16* HBF = (_Float16*)(ws + HBF_OFF);
  int* CNT = (int*)(ws + CNT_OFF);

  k_init<<<256, 256, 0, stream>>>(h0, HBF, CNT);
  k_castx<<<16384, 256, 0, stream>>>(x, AH);
  k_weights<<<8192, 256, 0, stream>>>(Wii, Wif, Wig, Wio, Whi, Whf, Whg, Who, WI, WH);
  k_gemm<<<dim3(256, 32), 256, 0, stream>>>(AH, WI, XP);
  k_rnn<<<256, 256, 0, stream>>>(XP, WH, c0, bI, bF, bG, bO, HBF, CNT, out);
}

// Round 3
// 3117.891 us; speedup vs baseline: 5.1580x; 1.0084x over previous
//
#include <hip/hip_runtime.h>
#include <cstdint>
#include <cstdio>

// CustomLSTM: B=64, T=512, D=H=1024.  f16 MFMA pipeline:
//   k_init    : h0 -> f16 ping buffer, zero sync flags
//   k_castx   : input_seq fp32 -> f16
//   k_weights : build permuted f16 Wi[4096][1024], Wh[4096][1024]
//               row perm p = nb*64 + uu*4 + gate  (gates interleaved so the 4
//               gate preacts of one (b,u) are contiguous in x_proj)
//   k_gemm    : x_proj[32768][4096] f16 = X @ Wi^T   (128x128 tile, mfma 16x16x32)
//   k_rnn     : persistent scan, 256 WGs (1/CU), Wh slice in LDS.
//               R2 sync: per-WG epoch FLAGS (plain relaxed sc1 stores, no RMW
//               hotspot); consumers poll 64 flags (1/lane) + __any vote; out
//               store + XP prefetch issued AFTER the flag store so they run
//               during the spin window, not inside the vmcnt drain.

typedef _Float16 half8 __attribute__((ext_vector_type(8)));
typedef _Float16 half4 __attribute__((ext_vector_type(4)));
typedef float f32x4 __attribute__((ext_vector_type(4)));

typedef __attribute__((address_space(1))) uint32_t gu32;
typedef __attribute__((address_space(3))) uint32_t lu32;

#define MFMA16(a, b, c) __builtin_amdgcn_mfma_f32_16x16x32_f16((a), (b), (c), 0, 0, 0)

// workspace layout (bytes)
#define XP_OFF   0ull                 // x_proj f16 [32768][4096]  = 256 MB
#define AH_OFF   268435456ull         // input f16  [32768][1024]  =  64 MB
#define WI_OFF   335544320ull         // Wi_perm f16 [4096][1024]  =   8 MB
#define WH_OFF   343932928ull         // Wh_perm f16 [4096][1024]  =   8 MB
#define HBF_OFF  352321536ull         // h f16 ping-pong [2][64][1024] = 256 KB
#define CNT_OFF  352583680ull         // flags: 4 groups x 64 ints
#define WS_NEED  352584704ull

#define RED_STRIDE 68                 // reduction row stride (floats), 16B-aligned

__device__ inline float sigmoid_f(float x) { return 1.f / (1.f + __expf(-x)); }
__device__ inline float tanh_f(float x) {
  float ax = fabsf(x);
  float e = __expf(-2.f * ax);          // in (0,1], no overflow
  float t = (1.f - e) / (1.f + e);
  return x < 0.f ? -t : t;
}

__global__ void k_init(const float* __restrict__ h0, _Float16* __restrict__ hbf,
                       int* __restrict__ cnt) {
  int i = blockIdx.x * 256 + threadIdx.x;
  hbf[i] = (_Float16)h0[i];
  if (blockIdx.x == 0) cnt[threadIdx.x] = 0;
}

__global__ void k_castx(const float* __restrict__ x, _Float16* __restrict__ xh) {
  size_t i = ((size_t)blockIdx.x * 256 + threadIdx.x) * 8;
  float4 a = *(const float4*)(x + i);
  float4 b = *(const float4*)(x + i + 4);
  half8 o = {(_Float16)a.x, (_Float16)a.y, (_Float16)a.z, (_Float16)a.w,
             (_Float16)b.x, (_Float16)b.y, (_Float16)b.z, (_Float16)b.w};
  *(half8*)(xh + i) = o;
}

// 8192 blocks: 0..4095 -> Wi rows, 4096..8191 -> Wh rows. 256 thr x 4 cols.
// perm row p = nb*64 + uu*4 + gate
__global__ void k_weights(const float* __restrict__ Wii, const float* __restrict__ Wif,
                          const float* __restrict__ Wig, const float* __restrict__ Wio,
                          const float* __restrict__ Whi, const float* __restrict__ Whf,
                          const float* __restrict__ Whg, const float* __restrict__ Who,
                          _Float16* __restrict__ WI, _Float16* __restrict__ WH) {
  int r = blockIdx.x;
  int p = r & 4095;
  int nb = p >> 6, uu = (p >> 2) & 15, gi = p & 3;
  int srow = nb * 16 + uu;
  const float* src;
  if (r < 4096) src = (gi == 0 ? Wii : gi == 1 ? Wif : gi == 2 ? Wig : Wio);
  else          src = (gi == 0 ? Whi : gi == 1 ? Whf : gi == 2 ? Whg : Who);
  src += (size_t)srow * 1024;
  _Float16* dst = (r < 4096 ? WI : WH) + (size_t)p * 1024;
  int c = threadIdx.x * 4;
  float4 v = *(const float4*)(src + c);
  half4 o = {(_Float16)v.x, (_Float16)v.y, (_Float16)v.z, (_Float16)v.w};
  *(half4*)(dst + c) = o;
}

// x_proj = A[32768][1024] @ B[4096][1024]^T, f16 out. 128x128 tile, BK=32.
__global__ __launch_bounds__(256) void k_gemm(const _Float16* __restrict__ A,
                                              const _Float16* __restrict__ B,
                                              _Float16* __restrict__ XPo) {
  __shared__ __align__(16) _Float16 As[128 * 32];
  __shared__ __align__(16) _Float16 Bs[128 * 32];
  const int tid = threadIdx.x;
  const int w = tid >> 6, l = tid & 63;
  const int wm = w >> 1, wn = w & 1;
  const int lm = l & 15, lq = l >> 4;
  const size_t m0 = (size_t)blockIdx.x * 128;
  const size_t n0 = (size_t)blockIdx.y * 128;

  f32x4 acc[4][4] = {};

  // staging: slot s (0..511) -> LDS bytes s*16; row = s>>2, kchunk = s&3
  const int r0 = tid >> 2, c0_ = tid & 3;
  const int r1 = (256 + tid) >> 2, c1_ = tid & 3;
  const _Float16* ga0 = A + (m0 + r0) * 1024 + c0_ * 8;
  const _Float16* ga1 = A + (m0 + r1) * 1024 + c1_ * 8;
  const _Float16* gb0 = B + (n0 + r0) * 1024 + c0_ * 8;
  const _Float16* gb1 = B + (n0 + r1) * 1024 + c1_ * 8;
  _Float16* laBase = As + (size_t)w * 512;   // wave-uniform LDS base (+lane*16 by HW)
  _Float16* lbBase = Bs + (size_t)w * 512;

  for (int kt = 0; kt < 32; ++kt) {
    const int k0 = kt * 32;
    __syncthreads();
    __builtin_amdgcn_global_load_lds((gu32*)(ga0 + k0), (lu32*)laBase, 16, 0, 0);
    __builtin_amdgcn_global_load_lds((gu32*)(ga1 + k0), (lu32*)(laBase + 2048), 16, 0, 0);
    __builtin_amdgcn_global_load_lds((gu32*)(gb0 + k0), (lu32*)lbBase, 16, 0, 0);
    __builtin_amdgcn_global_load_lds((gu32*)(gb1 + k0), (lu32*)(lbBase + 2048), 16, 0, 0);
    __syncthreads();

    half8 af[4], bf[4];
#pragma unroll
    for (int mi = 0; mi < 4; ++mi)
      af[mi] = *(const half8*)(As + (size_t)(wm * 64 + mi * 16 + lm) * 32 + lq * 8);
#pragma unroll
    for (int ni = 0; ni < 4; ++ni)
      bf[ni] = *(const half8*)(Bs + (size_t)(wn * 64 + ni * 16 + lm) * 32 + lq * 8);
#pragma unroll
    for (int mi = 0; mi < 4; ++mi)
#pragma unroll
      for (int ni = 0; ni < 4; ++ni)
        acc[mi][ni] = MFMA16(af[mi], bf[ni], acc[mi][ni]);
  }

#pragma unroll
  for (int mi = 0; mi < 4; ++mi) {
#pragma unroll
    for (int r = 0; r < 4; ++r) {
      size_t m = m0 + wm * 64 + mi * 16 + lq * 4 + r;  // D row=(l>>4)*4+r, col=l&15
      _Float16* orow = XPo + m * 4096 + n0 + wn * 64 + lm;
#pragma unroll
      for (int ni = 0; ni < 4; ++ni) orow[ni * 16] = (_Float16)acc[mi][ni][r];
    }
  }
}

// Persistent scan. WG = (mb = bid&3: 16 batches, nb = bid>>2: 16 units).
__global__ __launch_bounds__(256, 1) void k_rnn(
    const _Float16* __restrict__ XP, const _Float16* __restrict__ WH,
    const float* __restrict__ c0,
    const float* __restrict__ bI, const float* __restrict__ bF,
    const float* __restrict__ bG, const float* __restrict__ bO,
    _Float16* __restrict__ hbf, int* __restrict__ cnt, float* __restrict__ out) {
  __shared__ __align__(16) char smem[131072 + RED_STRIDE * 64 * 4];
  _Float16* wl = (_Float16*)smem;         // Wh slice swizzled [kc=128][row=64][8]
  float* red = (float*)(smem + 131072);   // [wave*16+batch][RED_STRIDE]

  const int tid = threadIdx.x;
  const int mb = blockIdx.x & 3;
  const int nb = blockIdx.x >> 2;

  // fill Wh LDS: slot s -> bytes s*16, row = s&63, kc = s>>6 (conflict-free writes)
  const _Float16* wsrc = WH + (size_t)nb * 64 * 1024;
#pragma unroll 4
  for (int it = 0; it < 32; ++it) {
    int s = it * 256 + tid;
    int row = s & 63, kc = s >> 6;
    *(half8*)(wl + (size_t)s * 8) = *(const half8*)(wsrc + (size_t)row * 1024 + kc * 8);
  }

  const int w = tid >> 6, l = tid & 63;
  const int lm = l & 15, lq = l >> 4;
  const int bl = tid >> 4, uu = tid & 15;
  const int bgrow = mb * 16 + bl;   // global batch (finalize role)
  const int u = nb * 16 + uu;       // global unit  (finalize role)

  float c = c0[(size_t)bgrow * 1024 + u];
  const float bias0 = bI[u], bias1 = bF[u], bias2 = bG[u], bias3 = bO[u];
  // interleaved-gate XP base: cols nb*64 + uu*4 + {0,1,2,3}
  const size_t xpth = (size_t)bgrow * 512 * 4096 + (size_t)nb * 64 + (size_t)uu * 4;
  int* flg = cnt + mb * 64;         // per-group flag array (64 ints)

  // A-operand base (halves) within one parity buffer, for this lane's wave slice
  const size_t habase = (size_t)(mb * 16 + lm) * 1024 + (size_t)lq * 8 + (size_t)w * 256;

  // prefetch step-0 x_proj contributions (4 contiguous f16)
  half4 xn = *(const half4*)(XP + xpth);

  __syncthreads();

  for (int t = 0; t < 512; ++t) {
    const float xv0 = (float)xn[0], xv1 = (float)xn[1];
    const float xv2 = (float)xn[2], xv3 = (float)xn[3];

    // ---- h loads: relaxed agent-scope (sc1, L2-bypass), 16 in flight ----
    const uint64_t* hq =
        (const uint64_t*)(hbf + (size_t)(t & 1) * 65536 + habase);
    uint64_t hraw[16];
#pragma unroll
    for (int kk = 0; kk < 8; ++kk) {
      hraw[2 * kk] = __hip_atomic_load(hq + (size_t)kk * 8, __ATOMIC_RELAXED,
                                       __HIP_MEMORY_SCOPE_AGENT);
      hraw[2 * kk + 1] = __hip_atomic_load(hq + (size_t)kk * 8 + 1, __ATOMIC_RELAXED,
                                           __HIP_MEMORY_SCOPE_AGENT);
    }

    // ---- gates partial: wave w covers k in [w*256, w*256+256) ----
    f32x4 a0 = {0.f, 0.f, 0.f, 0.f}, a1 = a0, a2 = a0, a3 = a0;
#pragma unroll
    for (int kk = 0; kk < 8; ++kk) {
      union { uint64_t q[2]; half8 v; } av_;
      av_.q[0] = hraw[2 * kk];
      av_.q[1] = hraw[2 * kk + 1];
      const int k0 = w * 256 + kk * 32;
      const _Float16* bb = wl + (size_t)(k0 / 8 + lq) * 512 + lm * 8;
      a0 = MFMA16(av_.v, *(const half8*)(bb), a0);
      a1 = MFMA16(av_.v, *(const half8*)(bb + 128), a1);
      a2 = MFMA16(av_.v, *(const half8*)(bb + 256), a2);
      a3 = MFMA16(av_.v, *(const half8*)(bb + 384), a3);
    }
#pragma unroll
    for (int r = 0; r < 4; ++r) {   // D: row=(l>>4)*4+r (batch), col=l&15
      float* rr = red + (size_t)(w * 16 + lq * 4 + r) * RED_STRIDE + lm;
      rr[0] = a0[r]; rr[16] = a1[r]; rr[32] = a2[r]; rr[48] = a3[r];
    }
    __syncthreads();

    // ---- finalize: thread = (batch bl, unit uu); gates at cols uu*4+g ----
    float p0 = xv0 + bias0, p1 = xv1 + bias1, p2 = xv2 + bias2, p3 = xv3 + bias3;
#pragma unroll
    for (int ww = 0; ww < 4; ++ww) {
      const float4 v = *(const float4*)(red + (size_t)(ww * 16 + bl) * RED_STRIDE + uu * 4);
      p0 += v.x; p1 += v.y; p2 += v.z; p3 += v.w;
    }
    float ig = sigmoid_f(p0), fg = sigmoid_f(p1), gg = tanh_f(p2), og = sigmoid_f(p3);
    c = fg * c + ig * gg;
    float h = og * tanh_f(c);

    if (t < 511) {
      // packed coherent h store (pairs of f16 via shfl; 4-byte relaxed agent store)
      uint32_t hbits = (uint32_t)__builtin_bit_cast(unsigned short, (_Float16)h);
      uint32_t other = (uint32_t)__shfl_xor((int)hbits, 1, 64);
      if ((uu & 1) == 0) {
        uint32_t packed = hbits | (other << 16);
        uint32_t* hx = (uint32_t*)(hbf + (size_t)((t + 1) & 1) * 65536);
        __hip_atomic_store(hx + ((size_t)bgrow * 1024 + u) / 2, packed,
                           __ATOMIC_RELAXED, __HIP_MEMORY_SCOPE_AGENT);
      }
      // drain ONLY the h stores, then publish this WG's epoch flag
      asm volatile("s_waitcnt vmcnt(0)" ::: "memory");
      __syncthreads();
      if (tid == 0)
        __hip_atomic_store(flg + nb, t + 1, __ATOMIC_RELAXED,
                           __HIP_MEMORY_SCOPE_AGENT);

      // these run during the spin window (not inside the drain):
      out[(size_t)(bgrow * 512 + t) * 1024 + u] = h;
      xn = *(const half4*)(XP + xpth + (size_t)(t + 1) * 4096);

      // ---- poll all 64 producer flags (1 per lane), every wave ----
      int fv;
      do {
        fv = __hip_atomic_load(flg + l, __ATOMIC_RELAXED, __HIP_MEMORY_SCOPE_AGENT);
      } while (__any(fv <= t));
    } else {
      out[(size_t)(bgrow * 512 + t) * 1024 + u] = h;
      out[33554432u + (size_t)bgrow * 1024 + u] = h;
      out[33554432u + 65536u + (size_t)bgrow * 1024 + u] = c;
    }
  }
}

extern "C" void kernel_launch(void* const* d_in, const int* in_sizes, int n_in,
                              void* d_out, int out_size, void* d_ws, size_t ws_size,
                              hipStream_t stream) {
  const float* x   = (const float*)d_in[0];
  const float* h0  = (const float*)d_in[1];
  const float* c0  = (const float*)d_in[2];
  const float* Wii = (const float*)d_in[3];
  const float* Whi = (const float*)d_in[4];
  const float* bI  = (const float*)d_in[5];
  const float* Wif = (const float*)d_in[6];
  const float* Whf = (const float*)d_in[7];
  const float* bF  = (const float*)d_in[8];
  const float* Wig = (const float*)d_in[9];
  const float* Whg = (const float*)d_in[10];
  const float* bG  = (const float*)d_in[11];
  const float* Wio = (const float*)d_in[12];
  const float* Who = (const float*)d_in[13];
  const float* bO  = (const float*)d_in[14];
  float* out = (float*)d_out;

  if (ws_size < WS_NEED) {
    fprintf(stderr, "kernel_launch: ws too small (%zu < %llu)\n", ws_size,
            (unsigned long long)WS_NEED);
    return;
  }
  char* ws = (char*)d_ws;
  _Float16* XP  = (_Float16*)(ws + XP_OFF);
  _Float16* AH  = (_Float16*)(ws + AH_OFF);
  _Float16* WI  = (_Float16*)(ws + WI_OFF);
  _Float16* WH  = (_Float16*)(ws + WH_OFF);
  _Float16* HBF = (_Float16*)(ws + HBF_OFF);
  int* CNT = (int*)(ws + CNT_OFF);

  k_init<<<256, 256, 0, stream>>>(h0, HBF, CNT);
  k_castx<<<16384, 256, 0, stream>>>(x, AH);
  k_weights<<<8192, 256, 0, stream>>>(Wii, Wif, Wig, Wio, Whi, Whf, Whg, Who, WI, WH);
  k_gemm<<<dim3(256, 32), 256, 0, stream>>>(AH, WI, XP);
  k_rnn<<<256, 256, 0, stream>>>(XP, WH, c0, bI, bF, bG, bO, HBF, CNT, out);
}